// Round 5
// baseline (860.912 us; speedup 1.0000x reference)
//
#include <hip/hip_runtime.h>

#define B_ 2048
#define T_ 256
#define F_ 128
#define H_ 64

typedef __attribute__((ext_vector_type(8))) short short8;   // 8 bf16
typedef __attribute__((ext_vector_type(4))) float f32x4;

// pack two floats to adjacent bf16 (RNE): low16 = a, high16 = b
__device__ __forceinline__ unsigned int rne2(float fa, float fb) {
    unsigned int ua = __float_as_uint(fa);
    unsigned int ub = __float_as_uint(fb);
    ua = ua + 0x7fffu + ((ua >> 16) & 1u);
    ub = ub + 0x7fffu + ((ub >> 16) & 1u);
    return (ua >> 16) | (ub & 0xffff0000u);
}
__device__ __forceinline__ float sigmoid_f(float v) {
    return __fdividef(1.0f, 1.0f + __expf(-v));
}
__device__ __forceinline__ float tanh_f(float v) {
    return 1.0f - __fdividef(2.0f, 1.0f + __expf(2.0f * v));  // overflow -> +/-1 correct
}
__device__ __forceinline__ float b2f(short v) {
    return __uint_as_float(((unsigned int)(unsigned short)v) << 16);
}

// Wave-per-row GRU (R4-passing layout, de-spilled, barrier-free T-loop).
// 256 threads = 4 waves; each WAVE owns ONE batch row, all 64 dims, all gates.
// Grid 512 blocks -> 2048 waves, 2 blocks/CU (LDS-capped), 2 waves/SIMD.
//
// gx: 8 timesteps per burst, A-row m carries timestep tau(m)=(m&3)+4*(m>>3)
//   (bit 2 of m is replication via identical load addresses). Gate at step
//   tau reads C row (tau&3)+8*(tau>>2) on lanes lq==2*(tau>>2), reg tau&3.
// gh: h_hi/h_lo in wave-private LDS rows {8g, 8g+1}; A-frag read row (c&11)
//   so A rows r, r^4 see identical data. 24 mfma/step, chunked per gate into
//   Acc[4] (+12 scalars) to keep VGPR demand ~235 < 256 (R4 spilled at ~260:
//   WRITE_SIZE 114MB of scratch).  w_hh B-frags loop-invariant in 96 VGPRs.
// Ordering: T-loop has NO cross-wave LDS traffic (ha is wave-private,
//   wihf/bias read-only) -> no barrier needed. Same-wave DS is in-order in
//   HW; the per-step asm memory fence stops compiler reordering of the
//   masked h-write past the next step's h-read (the R2/R3 failure mode).
__global__ __launch_bounds__(256, 2) void gru_fused(
    const float* __restrict__ x, const float* __restrict__ w_ih,
    const float* __restrict__ w_hh, const float* __restrict__ b_ih,
    const float* __restrict__ b_hh, const float* __restrict__ fc_w,
    const float* __restrict__ fc_b, float* __restrict__ out)
{
    __shared__ __align__(16) short wihf[12 * 4 * 64 * 8];   // 48 KB w_ih B-frags (bf16)
    __shared__ __align__(16) short ha[4][16][72];           // per-wave h rows (pad 72)
    __shared__ float bias_l[12][16];                        // gx bias per (tile, c)

    const int tid = threadIdx.x;
    const int wv  = tid >> 6;          // 0..3 (wave = batch row)
    const int l   = tid & 63;
    const int c   = l & 15;            // column within tile
    const int lq  = l >> 4;            // lane group 0..3
    const int row = blockIdx.x * 4 + wv;

    // ---- stage w_ih B-frags: slot s=(tile*4+ks)*64+L, el e = w_ih[tile*16+(L&15)][ks*32+(L>>4)*8+e]
    for (int s = tid; s < 12 * 4 * 64; s += 256) {
        const int n = s >> 8, ks = (s >> 6) & 3, L = s & 63;
        const float* wp = w_ih + (n * 16 + (L & 15)) * F_ + ks * 32 + ((L >> 4) * 8);
        const float4 a = *(const float4*)wp;
        const float4 b = *(const float4*)(wp + 4);
        union { short8 v; unsigned int u[4]; } fr;
        fr.u[0] = rne2(a.x, a.y); fr.u[1] = rne2(a.z, a.w);
        fr.u[2] = rne2(b.x, b.y); fr.u[3] = rne2(b.z, b.w);
        *(short8*)&wihf[s * 8] = fr.v;
    }
    // ---- zero h rows (h0 = 0; unused rows stay zero forever)
    for (int i = tid; i < 4 * 16 * 72; i += 256) ((short*)ha)[i] = 0;
    // ---- stage gx bias table: b_ih (+ b_hh for r,z tiles)
    if (tid < 192) {
        const int t = tid >> 4, cc = tid & 15;
        const int d = t * 16 + cc;
        bias_l[t][cc] = b_ih[d] + (t < 8 ? b_hh[d] : 0.0f);
    }

    // ---- per-lane n-gate recurrent bias
    float bnh[4];
    #pragma unroll
    for (int i = 0; i < 4; ++i) bnh[i] = b_hh[128 + i * 16 + c];

    // ---- w_hh B-frags -> registers (loop-invariant): whf[t][k2]
    // el e = w_hh[t*16 + c][k2*32 + lq*8 + e]
    short8 whf[12][2];
    #pragma unroll
    for (int t = 0; t < 12; ++t) {
        #pragma unroll
        for (int k2 = 0; k2 < 2; ++k2) {
            const float* wp = w_hh + (t * 16 + c) * H_ + k2 * 32 + lq * 8;
            const float4 a = *(const float4*)wp;
            const float4 b = *(const float4*)(wp + 4);
            union { short8 v; unsigned int u[4]; } fr;
            fr.u[0] = rne2(a.x, a.y); fr.u[1] = rne2(a.z, a.w);
            fr.u[2] = rne2(b.x, b.y); fr.u[3] = rne2(b.z, b.w);
            whf[t][k2] = fr.v;
        }
    }

    // A-side x mapping: lane carries timestep tau(c) = (c&3) + 4*(c>>3)
    // (bit 2 of c is replication: lanes c and c^4 load identical addresses)
    const int tau_c = (c & 3) | ((c >> 3) << 2);
    const float* xlane = x + ((size_t)row * T_ + tau_c) * F_ + lq * 8;
    short* hap = &ha[wv][0][0];
    const int ha_rd = (c & 11) * 72 + lq * 8;   // bit2-masked A-frag read base

    __syncthreads();   // wihf + zeroed ha + bias_l visible (the ONLY barrier)

    // ---- x staging: Xh reused; load ks01 -> cvt -> load ks23 -> cvt
    float4 Xh[4];
    short8 af[4];
    auto loadx = [&](const float* lp, int ksb) {
        #pragma unroll
        for (int k2 = 0; k2 < 2; ++k2) {
            Xh[2 * k2]     = *(const float4*)(lp + (ksb + k2) * 32);
            Xh[2 * k2 + 1] = *(const float4*)(lp + (ksb + k2) * 32 + 4);
        }
    };
    auto cvt2 = [&](int ksb) {
        #pragma unroll
        for (int k2 = 0; k2 < 2; ++k2) {
            union { short8 v; unsigned int u[4]; } fr;
            fr.u[0] = rne2(Xh[2 * k2].x,     Xh[2 * k2].y);
            fr.u[1] = rne2(Xh[2 * k2].z,     Xh[2 * k2].w);
            fr.u[2] = rne2(Xh[2 * k2 + 1].x, Xh[2 * k2 + 1].y);
            fr.u[3] = rne2(Xh[2 * k2 + 1].z, Xh[2 * k2 + 1].w);
            af[ksb + k2] = fr.v;
        }
    };
    loadx(xlane, 0); cvt2(0); loadx(xlane, 2); cvt2(2);

    f32x4 GXA[12];
    const f32x4 zc = {0.f, 0.f, 0.f, 0.f};
    auto burst = [&]() {   // gx for 8 steps: C row m -> step 8*macro + tau(m)
        #pragma unroll
        for (int t = 0; t < 12; ++t) {
            const float bv = bias_l[t][c];
            GXA[t] = (f32x4){bv, bv, bv, bv};
        }
        #pragma unroll
        for (int ks = 0; ks < 4; ++ks) {
            #pragma unroll
            for (int t = 0; t < 12; ++t)
                GXA[t] = __builtin_amdgcn_mfma_f32_16x16x32_bf16(
                    af[ks], *(const short8*)&wihf[(t * 4 + ks) * 512 + l * 8], GXA[t], 0, 0, 0);
        }
    };
    burst();

    #pragma unroll 1
    for (int m = 0; m < 32; ++m) {
        #pragma unroll
        for (int t2 = 0; t2 < 2; ++t2) {          // tau group: h rows 8*t2, 8*t2+1
            #pragma unroll
            for (int si = 0; si < 4; ++si) {
                const int tau = t2 * 4 + si;
                const int g2  = ((tau + 1) & 7) >> 2;   // next step's row group
                // ---- h A-frags (rows 8*t2, 8*t2+1 fresh; bit2-masked read)
                const short8 hA0 = *(const short8*)&hap[ha_rd];
                const short8 hA1 = *(const short8*)&hap[ha_rd + 32];
                // ---- h_prev for gate lanes (hi+lo from the fresh rows)
                float hp[4];
                #pragma unroll
                for (int i = 0; i < 4; ++i)
                    hp[i] = b2f(hap[(8 * t2) * 72 + i * 16 + c]) +
                            b2f(hap[(8 * t2 + 1) * 72 + i * 16 + c]);
                // ---- gh: 24 MFMA chunked per gate (4 accs + 12 scalars live)
                float grs[4], gzs[4], gns[4];
                #pragma unroll
                for (int g = 0; g < 3; ++g) {
                    f32x4 Acc[4];
                    #pragma unroll
                    for (int t4 = 0; t4 < 4; ++t4)
                        Acc[t4] = __builtin_amdgcn_mfma_f32_16x16x32_bf16(
                            hA0, whf[g * 4 + t4][0], zc, 0, 0, 0);
                    #pragma unroll
                    for (int t4 = 0; t4 < 4; ++t4)
                        Acc[t4] = __builtin_amdgcn_mfma_f32_16x16x32_bf16(
                            hA1, whf[g * 4 + t4][1], Acc[t4], 0, 0, 0);
                    if (lq == 2 * t2) {
                        #pragma unroll
                        for (int i = 0; i < 4; ++i) {
                            const float v = Acc[i][0] + Acc[i][1];
                            if (g == 0) grs[i] = v;
                            else if (g == 1) gzs[i] = v;
                            else gns[i] = v;
                        }
                    }
                }
                // ---- x prefetch for next macro (staged through Xh)
                if (tau == 1 && m < 31)
                    loadx(xlane + (size_t)(8 * (m + 1)) * F_, 0);
                if (tau == 3 && m < 31) {
                    cvt2(0);
                    loadx(xlane + (size_t)(8 * (m + 1)) * F_, 2);
                }
                if (tau == 5 && m < 31)
                    cvt2(2);
                // ---- gates on lanes lq == 2*t2, C reg si
                if (lq == 2 * t2) {
                    #pragma unroll
                    for (int i = 0; i < 4; ++i) {
                        const float r = sigmoid_f(GXA[i][si] + grs[i]);
                        const float z = sigmoid_f(GXA[4 + i][si] + gzs[i]);
                        const float n = tanh_f(GXA[8 + i][si] + r * (gns[i] + bnh[i]));
                        const float hn = n + z * (hp[i] - n);
                        const unsigned int uh = __float_as_uint(hn);
                        const unsigned int rr = uh + 0x7fffu + ((uh >> 16) & 1u);
                        const float hif = __uint_as_float(rr & 0xffff0000u);
                        const float lof = hn - hif;
                        const unsigned int ul = __float_as_uint(lof);
                        const unsigned int r2 = ul + 0x7fffu + ((ul >> 16) & 1u);
                        hap[(8 * g2)     * 72 + i * 16 + c] = (short)(rr >> 16);
                        hap[(8 * g2 + 1) * 72 + i * 16 + c] = (short)(r2 >> 16);
                    }
                }
                asm volatile("" ::: "memory");   // no compiler reorder of h write->read
            }
        }
        if (m < 31) burst();   // gx for next 8-step macro
    }

    // ===== epilogue: final h (after step 255) is in rows 0,1 =====
    {
        const float hv = b2f(hap[l]) + b2f(hap[72 + l]);
        float partial = hv * fc_w[l];
        #pragma unroll
        for (int msk = 1; msk <= 32; msk <<= 1) partial += __shfl_xor(partial, msk, 64);
        if (l == 0) out[row] = partial + fc_b[0];
    }
}

extern "C" void kernel_launch(void* const* d_in, const int* in_sizes, int n_in,
                              void* d_out, int out_size, void* d_ws, size_t ws_size,
                              hipStream_t stream)
{
    (void)in_sizes; (void)n_in; (void)out_size; (void)d_ws; (void)ws_size;
    const float* x    = (const float*)d_in[0];
    const float* w_ih = (const float*)d_in[1];
    const float* w_hh = (const float*)d_in[2];
    const float* b_ih = (const float*)d_in[3];
    const float* b_hh = (const float*)d_in[4];
    const float* fc_w = (const float*)d_in[5];
    const float* fc_b = (const float*)d_in[6];
    float* out = (float*)d_out;

    gru_fused<<<dim3(B_ / 4), 256, 0, stream>>>(
        x, w_ih, w_hh, b_ih, b_hh, fc_w, fc_b, out);
}

// Round 6
// 654.774 us; speedup vs baseline: 1.3148x; 1.3148x over previous
//
#include <hip/hip_runtime.h>

#define B_ 2048
#define T_ 256
#define F_ 128
#define H_ 64

typedef __attribute__((ext_vector_type(8))) short short8;   // 8 bf16
typedef __attribute__((ext_vector_type(4))) float f32x4;

// pack two floats to adjacent bf16 (RNE): low16 = a, high16 = b
__device__ __forceinline__ unsigned int rne2(float fa, float fb) {
    unsigned int ua = __float_as_uint(fa);
    unsigned int ub = __float_as_uint(fb);
    ua = ua + 0x7fffu + ((ua >> 16) & 1u);
    ub = ub + 0x7fffu + ((ub >> 16) & 1u);
    return (ua >> 16) | (ub & 0xffff0000u);
}
__device__ __forceinline__ float sigmoid_f(float v) {
    return __fdividef(1.0f, 1.0f + __expf(-v));
}
__device__ __forceinline__ float tanh_f(float v) {
    return 1.0f - __fdividef(2.0f, 1.0f + __expf(2.0f * v));  // overflow -> +/-1 correct
}

// Wave-per-row GRU, all-lane gate edition (barrier-free; fence-only ordering
// verified by R5's pass).
// 256 threads = 4 waves; each WAVE owns ONE batch row. Grid 512 blocks,
// 2 blocks/CU (LDS 65KB), 2 independent waves/SIMD.
//
// Each lane permanently owns hidden dim d = lq*16+c; h[d] lives in ONE fp32
// register (hcur). Per step:
//   gh: A rows (c&1)+2*db -> row parity = hi/lo; C reg0 = hi@W, reg1 = lo@W
//       on EVERY lane group. 12 N-tiles x 2 K-halves = 24 mfma, B-frags in
//       96 VGPRs. Lane's gh = cndmask-select tile (g*4+lq), regs 0+1.
//   gx: bursts of 4 steps, A row m carries tau = m&3 (4x replication) ->
//       step tau's gx at C reg tau on every lane group. 48 mfma / 4 steps.
//       Burst C (48 regs, transient) spills to gxl LDS (lq==0 rows 0-3);
//       steps read 3 scalars (broadcast, conflict-free). This removes the
//       48-reg steady-state block that made R4/R5 spill (WRITE_SIZE 122MB).
//   gates: ALL 64 lanes, one dim each; h write = 2 ds_write_b16 (merge-
//       friendly layout); h read = 2 ds_read_b128 (2-way = free).
__global__ __launch_bounds__(256, 2) void gru_fused(
    const float* __restrict__ x, const float* __restrict__ w_ih,
    const float* __restrict__ w_hh, const float* __restrict__ b_ih,
    const float* __restrict__ b_hh, const float* __restrict__ fc_w,
    const float* __restrict__ fc_b, float* __restrict__ out)
{
    __shared__ __align__(16) short wihf[12 * 4 * 64 * 8];   // 48 KB w_ih B-frags
    __shared__ __align__(16) short ha[4][4][72];            // h hi/lo x dbuf, pad 72
    __shared__ __align__(16) float gxl[4][960];             // gx spill: t*80+tau*20+c
    __shared__ float bias_l[12][16];

    const int tid = threadIdx.x;
    const int wv  = tid >> 6;          // 0..3 (wave = batch row)
    const int l   = tid & 63;
    const int c   = l & 15;
    const int lq  = l >> 4;            // 0..3
    const int row = blockIdx.x * 4 + wv;
    const int d   = lq * 16 + c;       // this lane's hidden dim (all 64 distinct)

    // ---- stage w_ih B-frags (R5-verified mapping)
    for (int s = tid; s < 12 * 4 * 64; s += 256) {
        const int n = s >> 8, ks = (s >> 6) & 3, L = s & 63;
        const float* wp = w_ih + (n * 16 + (L & 15)) * F_ + ks * 32 + ((L >> 4) * 8);
        const float4 a = *(const float4*)wp;
        const float4 b = *(const float4*)(wp + 4);
        union { short8 v; unsigned int u[4]; } fr;
        fr.u[0] = rne2(a.x, a.y); fr.u[1] = rne2(a.z, a.w);
        fr.u[2] = rne2(b.x, b.y); fr.u[3] = rne2(b.z, b.w);
        *(short8*)&wihf[s * 8] = fr.v;
    }
    // ---- zero h buffers
    for (int i = tid; i < 4 * 4 * 72; i += 256) ((short*)ha)[i] = 0;
    // ---- gx bias table: b_ih (+ b_hh for r,z)
    if (tid < 192) {
        const int t = tid >> 4, cc = tid & 15;
        const int dd = t * 16 + cc;
        bias_l[t][cc] = b_ih[dd] + (t < 8 ? b_hh[dd] : 0.0f);
    }

    const float bnh = b_hh[128 + d];   // n-gate recurrent bias, lane's dim

    // ---- w_hh B-frags -> registers (loop-invariant, R5-verified mapping)
    short8 whf[12][2];
    #pragma unroll
    for (int t = 0; t < 12; ++t) {
        #pragma unroll
        for (int k2 = 0; k2 < 2; ++k2) {
            const float* wp = w_hh + (t * 16 + c) * H_ + k2 * 32 + lq * 8;
            const float4 a = *(const float4*)wp;
            const float4 b = *(const float4*)(wp + 4);
            union { short8 v; unsigned int u[4]; } fr;
            fr.u[0] = rne2(a.x, a.y); fr.u[1] = rne2(a.z, a.w);
            fr.u[2] = rne2(b.x, b.y); fr.u[3] = rne2(b.z, b.w);
            whf[t][k2] = fr.v;
        }
    }

    // A-side x: row m carries tau = m&3 (lanes c, c^4, c^8, c^12 same addr)
    const float* xlane = x + ((size_t)row * T_ + (c & 3)) * F_ + lq * 8;
    short* hap = &ha[wv][0][0];
    float* gxw = &gxl[wv][0];
    const int ha_rd0 = (c & 1) * 72 + lq * 8;   // +144 for dbuf 1, +32 for k2=1

    __syncthreads();   // staging visible (the ONLY barrier)

    // ---- x staging
    float4 Xh[4];
    short8 af[4];
    auto loadx = [&](const float* lp, int ksb) {
        #pragma unroll
        for (int k2 = 0; k2 < 2; ++k2) {
            Xh[2 * k2]     = *(const float4*)(lp + (ksb + k2) * 32);
            Xh[2 * k2 + 1] = *(const float4*)(lp + (ksb + k2) * 32 + 4);
        }
    };
    auto cvt2 = [&](int ksb) {
        #pragma unroll
        for (int k2 = 0; k2 < 2; ++k2) {
            union { short8 v; unsigned int u[4]; } fr;
            fr.u[0] = rne2(Xh[2 * k2].x,     Xh[2 * k2].y);
            fr.u[1] = rne2(Xh[2 * k2].z,     Xh[2 * k2].w);
            fr.u[2] = rne2(Xh[2 * k2 + 1].x, Xh[2 * k2 + 1].y);
            fr.u[3] = rne2(Xh[2 * k2 + 1].z, Xh[2 * k2 + 1].w);
            af[ksb + k2] = fr.v;
        }
    };
    loadx(xlane, 0); cvt2(0); loadx(xlane, 2); cvt2(2);

    const f32x4 zc = {0.f, 0.f, 0.f, 0.f};
    auto burst = [&]() {   // gx for 4 steps -> spill rows 0..3 to gxl
        f32x4 GXC[12];
        #pragma unroll
        for (int t = 0; t < 12; ++t) {
            const float bv = bias_l[t][c];
            GXC[t] = (f32x4){bv, bv, bv, bv};
        }
        #pragma unroll
        for (int ks = 0; ks < 4; ++ks) {
            #pragma unroll
            for (int t = 0; t < 12; ++t)
                GXC[t] = __builtin_amdgcn_mfma_f32_16x16x32_bf16(
                    af[ks], *(const short8*)&wihf[(t * 4 + ks) * 512 + l * 8], GXC[t], 0, 0, 0);
        }
        if (lq == 0) {
            #pragma unroll
            for (int t = 0; t < 12; ++t)
                #pragma unroll
                for (int i = 0; i < 4; ++i)
                    gxw[t * 80 + i * 20 + c] = GXC[t][i];
        }
        asm volatile("" ::: "memory");
    };
    burst();

    float hcur = 0.0f;   // lane's h[d], full fp32, never leaves the register

    #pragma unroll 1
    for (int m = 0; m < 64; ++m) {
        #pragma unroll
        for (int si = 0; si < 4; ++si) {
            const int db = si & 1;               // compile-time double-buffer
            // ---- h A-frags: row parity = hi/lo
            const short8 hA0 = *(const short8*)&hap[ha_rd0 + db * 144];
            const short8 hA1 = *(const short8*)&hap[ha_rd0 + db * 144 + 32];
            // ---- gx scalars for this step (broadcast reads)
            const float gxr = gxw[(0 + lq) * 80 + si * 20 + c];
            const float gxz = gxw[(4 + lq) * 80 + si * 20 + c];
            const float gxn = gxw[(8 + lq) * 80 + si * 20 + c];
            // ---- gh: 24 MFMA in 3 gate chunks; lane selects tile g*4+lq
            float gh[3];
            #pragma unroll
            for (int g = 0; g < 3; ++g) {
                f32x4 Acc[4];
                #pragma unroll
                for (int t4 = 0; t4 < 4; ++t4)
                    Acc[t4] = __builtin_amdgcn_mfma_f32_16x16x32_bf16(
                        hA0, whf[g * 4 + t4][0], zc, 0, 0, 0);
                #pragma unroll
                for (int t4 = 0; t4 < 4; ++t4)
                    Acc[t4] = __builtin_amdgcn_mfma_f32_16x16x32_bf16(
                        hA1, whf[g * 4 + t4][1], Acc[t4], 0, 0, 0);
                const float s0 = Acc[0][0] + Acc[0][1];   // hi-row + lo-row
                const float s1 = Acc[1][0] + Acc[1][1];
                const float s2 = Acc[2][0] + Acc[2][1];
                const float s3 = Acc[3][0] + Acc[3][1];
                const float a01 = (lq & 1) ? s1 : s0;
                const float a23 = (lq & 1) ? s3 : s2;
                gh[g] = (lq & 2) ? a23 : a01;
            }
            // ---- x prefetch for next macro
            if (si == 1 && m < 63) loadx(xlane + (size_t)(4 * (m + 1)) * F_, 0);
            if (si == 2 && m < 63) { cvt2(0); loadx(xlane + (size_t)(4 * (m + 1)) * F_, 2); }
            if (si == 3 && m < 63) cvt2(2);
            // ---- gate (ALL 64 lanes, one dim each)
            const float r = sigmoid_f(gxr + gh[0]);
            const float z = sigmoid_f(gxz + gh[1]);
            const float n = tanh_f(gxn + r * (gh[2] + bnh));
            hcur = n + z * (hcur - n);
            // ---- split hi/lo bf16, write to the other buffer
            const unsigned int uh = __float_as_uint(hcur);
            const unsigned int rr = uh + 0x7fffu + ((uh >> 16) & 1u);
            const float hif = __uint_as_float(rr & 0xffff0000u);
            const float lof = hcur - hif;
            const unsigned int ul = __float_as_uint(lof);
            const unsigned int r2 = ul + 0x7fffu + ((ul >> 16) & 1u);
            const int wb = (db ^ 1) * 144;       // rows {2*(db^1), 2*(db^1)+1}
            hap[wb + d]      = (short)(rr >> 16);
            hap[wb + 72 + d] = (short)(r2 >> 16);
            asm volatile("" ::: "memory");       // no ds write->read reorder
        }
        if (m < 63) burst();   // gx for next 4 steps
    }

    // ===== epilogue: each lane holds final h[d] in hcur =====
    {
        float partial = hcur * fc_w[d];
        #pragma unroll
        for (int msk = 1; msk <= 32; msk <<= 1) partial += __shfl_xor(partial, msk, 64);
        if (l == 0) out[row] = partial + fc_b[0];
    }
}

extern "C" void kernel_launch(void* const* d_in, const int* in_sizes, int n_in,
                              void* d_out, int out_size, void* d_ws, size_t ws_size,
                              hipStream_t stream)
{
    (void)in_sizes; (void)n_in; (void)out_size; (void)d_ws; (void)ws_size;
    const float* x    = (const float*)d_in[0];
    const float* w_ih = (const float*)d_in[1];
    const float* w_hh = (const float*)d_in[2];
    const float* b_ih = (const float*)d_in[3];
    const float* b_hh = (const float*)d_in[4];
    const float* fc_w = (const float*)d_in[5];
    const float* fc_b = (const float*)d_in[6];
    float* out = (float*)d_out;

    gru_fused<<<dim3(B_ / 4), 256, 0, stream>>>(
        x, w_ih, w_hh, b_ih, b_hh, fc_w, fc_b, out);
}